// Round 1
// baseline (170.588 us; speedup 1.0000x reference)
//
#include <hip/hip_runtime.h>
#include <hip/hip_bf16.h>

// corr[b,h,w] = sum_c fmap1[b,c,h,w] * mean_{k,l} fmap2[b,c,k,l]
// B=8, C=256, H=W=96, HW=9216. Output [B,1,H,W] f32.

#define B_ 8
#define C_ 256
#define HW_ 9216   // 96*96

// ---------------- Kernel A: m2[b,c] = mean over HW of fmap2[b,c,:,:] -------
// One block per (b,c). 256 threads, each reads 9 float4 (9*4*256 = 9216).
__global__ __launch_bounds__(256) void mean2_kernel(const float* __restrict__ f2,
                                                    float* __restrict__ m2) {
    const int bc = blockIdx.x;                       // 0..2047
    const float4* p = (const float4*)(f2 + (size_t)bc * HW_);
    const int t = threadIdx.x;

    float s = 0.f;
#pragma unroll
    for (int k = 0; k < 9; ++k) {
        float4 v = p[t + k * 256];
        s += (v.x + v.y) + (v.z + v.w);
    }
    // wave64 reduce
#pragma unroll
    for (int off = 32; off > 0; off >>= 1)
        s += __shfl_down(s, off, 64);

    __shared__ float ws[4];
    const int wid = t >> 6, lane = t & 63;
    if (lane == 0) ws[wid] = s;
    __syncthreads();
    if (t == 0) {
        float tot = (ws[0] + ws[1]) + (ws[2] + ws[3]);
        m2[bc] = tot * (1.0f / (float)HW_);
    }
}

// ---------------- Kernel B: corr[b,hw] = sum_c fmap1[b,c,hw]*m2[b,c] -------
// Grid: b (8) x hw-chunk (9, 1024 positions each) x c-chunk (8, 32 ch each).
// Each thread: 4 consecutive hw positions (float4), loops 32 channels,
// atomicAdds partial sums into zero-initialized d_out.
__global__ __launch_bounds__(256) void corr_kernel(const float* __restrict__ f1,
                                                   const float* __restrict__ m2,
                                                   float* __restrict__ out) {
    const int lin   = blockIdx.x;          // 0..575
    const int b     = lin / 72;
    const int rem   = lin % 72;
    const int hwblk = rem / 8;             // 0..8
    const int cblk  = rem % 8;             // 0..7
    const int c0    = cblk * 32;
    const int pos   = hwblk * 1024 + threadIdx.x * 4;

    const float* f1base = f1 + ((size_t)b * C_ + c0) * HW_ + pos;
    const float* m2base = m2 + b * C_ + c0;

    float4 acc = {0.f, 0.f, 0.f, 0.f};
#pragma unroll 8
    for (int i = 0; i < 32; ++i) {
        float  s = m2base[i];                                  // uniform -> s_load
        float4 v = *(const float4*)(f1base + (size_t)i * HW_); // coalesced 16B/lane
        acc.x += v.x * s;
        acc.y += v.y * s;
        acc.z += v.z * s;
        acc.w += v.w * s;
    }

    float* o = out + (size_t)b * HW_ + pos;
    atomicAdd(o + 0, acc.x);
    atomicAdd(o + 1, acc.y);
    atomicAdd(o + 2, acc.z);
    atomicAdd(o + 3, acc.w);
}

extern "C" void kernel_launch(void* const* d_in, const int* in_sizes, int n_in,
                              void* d_out, int out_size, void* d_ws, size_t ws_size,
                              hipStream_t stream) {
    const float* f1 = (const float*)d_in[0];
    const float* f2 = (const float*)d_in[1];
    float* out = (float*)d_out;
    float* m2  = (float*)d_ws;      // B_*C_ = 2048 floats = 8 KB

    // d_out is poisoned 0xAA before every timed launch — zero it (async, capturable).
    hipMemsetAsync(d_out, 0, (size_t)out_size * sizeof(float), stream);

    mean2_kernel<<<B_ * C_, 256, 0, stream>>>(f2, m2);
    corr_kernel<<<576, 256, 0, stream>>>(f1, m2, out);
}

// Round 2
// 167.034 us; speedup vs baseline: 1.0213x; 1.0213x over previous
//
#include <hip/hip_runtime.h>
#include <hip/hip_bf16.h>

// corr[b,h,w] = sum_c fmap1[b,c,h,w] * mean_{k,l} fmap2[b,c,k,l]
// B=8, C=256, H=W=96, HW=9216. Output [B,1,H,W] f32 (73728 elements).

#define B_ 8
#define C_ 256
#define HW_ 9216   // 96*96

// ---------------- Kernel A: m2[b,c] = mean over HW of fmap2[b,c,:,:] -------
// One block per (b,c). 256 threads, each reads 9 float4 (9*4*256 = 9216).
// Blocks 0..71 additionally zero d_out (72*256 float4 = 73728 floats),
// replacing a separate memset dispatch. Stream order guarantees it lands
// before corr_kernel's atomics.
__global__ __launch_bounds__(256) void mean2_kernel(const float* __restrict__ f2,
                                                    float* __restrict__ m2,
                                                    float* __restrict__ out) {
    const int bc = blockIdx.x;                       // 0..2047
    const int t  = threadIdx.x;

    if (bc < 72) {
        ((float4*)out)[bc * 256 + t] = make_float4(0.f, 0.f, 0.f, 0.f);
    }

    const float4* p = (const float4*)(f2 + (size_t)bc * HW_);
    float s = 0.f;
#pragma unroll
    for (int k = 0; k < 9; ++k) {
        float4 v = p[t + k * 256];
        s += (v.x + v.y) + (v.z + v.w);
    }
    // wave64 butterfly-free down-reduce
#pragma unroll
    for (int off = 32; off > 0; off >>= 1)
        s += __shfl_down(s, off, 64);

    __shared__ float ws[4];
    const int wid = t >> 6, lane = t & 63;
    if (lane == 0) ws[wid] = s;
    __syncthreads();
    if (t == 0) {
        float tot = (ws[0] + ws[1]) + (ws[2] + ws[3]);
        m2[bc] = tot * (1.0f / (float)HW_);
    }
}

// ---------------- Kernel B: corr[b,hw] = sum_c fmap1[b,c,hw]*m2[b,c] -------
// Grid: b (8) x hw-chunk (9, 1024 positions) x c-chunk (16, 16 ch each)
//     = 1152 blocks (4.5 blocks/CU, 18 waves/CU).
// Each thread: 4 consecutive hw positions (float4), 16 fully-unrolled
// independent channel loads, then 4 f32 atomicAdds into zeroed d_out.
__global__ __launch_bounds__(256) void corr_kernel(const float* __restrict__ f1,
                                                   const float* __restrict__ m2,
                                                   float* __restrict__ out) {
    const int lin   = blockIdx.x;          // 0..1151
    const int b     = lin / 144;
    const int rem   = lin % 144;
    const int hwblk = rem / 16;            // 0..8
    const int cblk  = rem % 16;            // 0..15
    const int c0    = cblk * 16;
    const int pos   = hwblk * 1024 + threadIdx.x * 4;

    const float* f1base = f1 + ((size_t)b * C_ + c0) * HW_ + pos;
    const float* m2base = m2 + b * C_ + c0;

    float4 acc = {0.f, 0.f, 0.f, 0.f};
#pragma unroll
    for (int i = 0; i < 16; ++i) {
        float  s = m2base[i];                                  // uniform -> s_load
        float4 v = *(const float4*)(f1base + (size_t)i * HW_); // coalesced 16B/lane
        acc.x += v.x * s;
        acc.y += v.y * s;
        acc.z += v.z * s;
        acc.w += v.w * s;
    }

    float* o = out + (size_t)b * HW_ + pos;
    atomicAdd(o + 0, acc.x);
    atomicAdd(o + 1, acc.y);
    atomicAdd(o + 2, acc.z);
    atomicAdd(o + 3, acc.w);
}

extern "C" void kernel_launch(void* const* d_in, const int* in_sizes, int n_in,
                              void* d_out, int out_size, void* d_ws, size_t ws_size,
                              hipStream_t stream) {
    const float* f1 = (const float*)d_in[0];
    const float* f2 = (const float*)d_in[1];
    float* out = (float*)d_out;
    float* m2  = (float*)d_ws;      // B_*C_ = 2048 floats = 8 KB

    mean2_kernel<<<B_ * C_, 256, 0, stream>>>(f2, m2, out);
    corr_kernel<<<1152, 256, 0, stream>>>(f1, m2, out);
}